// Round 3
// baseline (211.420 us; speedup 1.0000x reference)
//
#include <hip/hip_runtime.h>
#include <hip/hip_bf16.h>

// Problem shape (fixed by the reference setup_inputs)
constexpr int B = 16, F = 16, H = 256, W = 256;
constexpr int HW = H * W;               // 65536
constexpr int SPATIAL = B * HW;         // 1,048,576 spatial locations
constexpr int NBLOCKS = 1024;
constexpr int NTHREADS = 512;           // 8 waves/block
constexpr int NVALS = 65;               // s[16], c[16], dtot[16], sall[16], call
constexpr int PLANE4 = HW / 4;          // 16384 float4 (or mask-dwords) per (b,f) plane
constexpr int BSTRIDE4 = F * PLANE4;    // 262144 per batch index
constexpr int FH = 8;                   // features per half-wave

__inline__ __device__ float reduce32(float v) {
    // reduce within each 32-lane half of the wave64
    #pragma unroll
    for (int o = 16; o > 0; o >>= 1) v += __shfl_down(v, o, 32);
    return v;
}

// Each 32-lane half-wave owns 32 consecutive float4-groups for 8 of the 16
// features. 1024 blocks * 8 waves * 32 groups = 262144 groups = SPATIAL/4.
// f-split doubles wave count (8 waves/SIMD) to hide memory latency.
__global__ __launch_bounds__(NTHREADS, 8) void heatloss_main(
        const float4* __restrict__ inp, const float4* __restrict__ tgt,
        const unsigned int* __restrict__ msk, float* __restrict__ partials) {
    const int tid    = threadIdx.x;
    const int wave   = tid >> 6;
    const int lane   = tid & 63;
    const int lane32 = lane & 31;
    const int half   = lane >> 5;            // 0: f 0-7, 1: f 8-15
    const int g      = (blockIdx.x * 8 + wave) * 32 + lane32;  // float4-group id
    const int b      = g >> 14;              // g / PLANE4
    const int hw4    = g & (PLANE4 - 1);
    const int base   = b * BSTRIDE4 + hw4 + half * (FH * PLANE4);

    // Mask words for my 8 features (dword = 4 bool bytes).
    unsigned int m[FH];
    #pragma unroll
    for (int j = 0; j < FH; j++) m[j] = msk[base + j * PLANE4];

    unsigned int anyu = 0;
    #pragma unroll
    for (int j = 0; j < FH; j++) anyu |= m[j];
    anyu |= __shfl_xor(anyu, 32, 64);        // combine halves -> any over all 16 f
    const float af0 = (anyu & 0x000000FFu) ? 1.f : 0.f;
    const float af1 = (anyu & 0x0000FF00u) ? 1.f : 0.f;
    const float af2 = (anyu & 0x00FF0000u) ? 1.f : 0.f;
    const float af3 = (anyu & 0xFF000000u) ? 1.f : 0.f;
    const float call = (half == 0) ? (af0 + af1) + (af2 + af3) : 0.f;  // count once

    float s[FH], c[FH], dtot[FH], sall[FH];
    #pragma unroll
    for (int j = 0; j < FH; j++) {
        const float4 a = inp[base + j * PLANE4];
        const float4 t = tgt[base + j * PLANE4];
        const float d0 = fabsf(a.x - t.x);
        const float d1 = fabsf(a.y - t.y);
        const float d2 = fabsf(a.z - t.z);
        const float d3 = fabsf(a.w - t.w);
        const unsigned int mm = m[j];
        const float m0 = (float)( mm        & 0xFFu);
        const float m1 = (float)((mm >> 8)  & 0xFFu);
        const float m2 = (float)((mm >> 16) & 0xFFu);
        const float m3 = (float)( mm >> 24);
        dtot[j] = (d0 + d1) + (d2 + d3);
        s[j]    = m0 * d0 + m1 * d1 + m2 * d2 + m3 * d3;
        c[j]    = (m0 + m1) + (m2 + m3);
        sall[j] = af0 * d0 + af1 * d1 + af2 * d2 + af3 * d3;
    }

    // Width-32 reduction (halves hold disjoint features), LDS across 8 waves.
    __shared__ float red[NTHREADS / 64][NVALS];
    const int fbase = half * FH;
    #pragma unroll
    for (int j = 0; j < FH; j++) {
        const float xs = reduce32(s[j]);
        const float xc = reduce32(c[j]);
        const float xd = reduce32(dtot[j]);
        const float xa = reduce32(sall[j]);
        if (lane32 == 0) {                   // lane 0 writes f 0-7, lane 32 writes f 8-15
            red[wave][ 0 + fbase + j] = xs;
            red[wave][16 + fbase + j] = xc;
            red[wave][32 + fbase + j] = xd;
            red[wave][48 + fbase + j] = xa;
        }
    }
    const float xcall = reduce32(call);
    if (lane == 0) red[wave][64] = xcall;
    __syncthreads();
    if (tid < NVALS) {
        float t = 0.f;
        #pragma unroll
        for (int w2 = 0; w2 < NTHREADS / 64; w2++) t += red[w2][tid];
        partials[tid * NBLOCKS + blockIdx.x] = t;   // layout [65][NBLOCKS]
    }
}

// 8 waves; each wave sums one value's 1024 partials with coalesced loads.
__global__ __launch_bounds__(512) void heatloss_finalize(
        const float* __restrict__ partials, float* __restrict__ out) {
    __shared__ float vals[NVALS];
    const int wave = threadIdx.x >> 6;   // 0..7
    const int lane = threadIdx.x & 63;
    for (int v = wave; v < NVALS; v += 8) {
        const float* p = partials + v * NBLOCKS;
        float x = 0.f;
        #pragma unroll
        for (int i = 0; i < NBLOCKS / 64; i++) x += p[i * 64 + lane];
        #pragma unroll
        for (int o = 32; o > 0; o >>= 1) x += __shfl_down(x, o, 64);
        if (lane == 0) vals[v] = x;
    }
    __syncthreads();
    if (threadIdx.x == 0) {
        const float Nf = (float)SPATIAL;  // per-feature element count (B*H*W)
        const float call = vals[64];
        float lf = 0.f, lbg = 0.f, lall = 0.f;
        #pragma unroll
        for (int f = 0; f < F; f++) {
            const float sf = vals[f], cf = vals[16 + f];
            const float dt = vals[32 + f], sa = vals[48 + f];
            lf += (cf > 0.f) ? sf / cf : 0.f;
            const float sbg = dt - sf, cbg = Nf - cf;
            lbg += (cbg > 0.f) ? sbg / cbg : 0.f;
            lall += (call > 0.f) ? sa / call : 0.f;
        }
        out[0] = (lf / 16.f + lbg / 16.f + lall / 16.f) / 3.f;
    }
}

extern "C" void kernel_launch(void* const* d_in, const int* in_sizes, int n_in,
                              void* d_out, int out_size, void* d_ws, size_t ws_size,
                              hipStream_t stream) {
    const float4*       inp = (const float4*)d_in[0];
    const float4*       tgt = (const float4*)d_in[1];
    const unsigned int* msk = (const unsigned int*)d_in[2];   // jnp.bool_ -> 1 byte each
    float* out      = (float*)d_out;
    float* partials = (float*)d_ws;   // NVALS * NBLOCKS floats = 266 KB

    heatloss_main<<<NBLOCKS, NTHREADS, 0, stream>>>(inp, tgt, msk, partials);
    heatloss_finalize<<<1, 512, 0, stream>>>(partials, out);
}

// Round 4
// 188.986 us; speedup vs baseline: 1.1187x; 1.1187x over previous
//
#include <hip/hip_runtime.h>
#include <hip/hip_bf16.h>

// Problem shape (fixed by the reference setup_inputs)
constexpr int B = 16, F = 16, H = 256, W = 256;
constexpr int HW = H * W;               // 65536
constexpr int SPATIAL = B * HW;         // 1,048,576 spatial locations
constexpr int NBLOCKS = 1024;
constexpr int NTHREADS = 1024;          // 16 waves/block
constexpr int NVALS = 65;               // s[16], c[16], dtot[16], sall[16], call
constexpr int PLANE4 = HW / 4;          // 16384 float4 (or mask-dwords) per (b,f) plane
constexpr int BSTRIDE4 = F * PLANE4;    // 262144 per batch index
constexpr int FQ = 4;                   // features per quarter-wave

// Each 16-lane quarter of a wave owns 16 consecutive float4-groups for 4 of
// the 16 features (q = lane>>4). All quarters share the same positions, so
// m_all is two shfl_xor ORs. 1024 blk * 16 waves * 16 groups = SPATIAL/4.
// Per-thread state (~16 accum + 4 mask + load bufs) fits 64 VGPRs -> no spill
// at 8 waves/SIMD (round-3 lesson: forced 64-reg cap + 32 accums = 47 MB spill).
__global__ __launch_bounds__(NTHREADS, 8) void heatloss_main(
        const float4* __restrict__ inp, const float4* __restrict__ tgt,
        const unsigned int* __restrict__ msk, float* __restrict__ partials) {
    const int tid  = threadIdx.x;
    const int wave = tid >> 6;               // 0..15
    const int lane = tid & 63;
    const int l16  = lane & 15;
    const int q    = lane >> 4;              // quarter: features q*4 .. q*4+3
    const int g    = (blockIdx.x * 16 + wave) * 16 + l16;   // float4-group id
    const int b    = g >> 14;                // g / PLANE4
    const int hw4  = g & (PLANE4 - 1);
    const int base = b * BSTRIDE4 + hw4 + q * (FQ * PLANE4);

    // Mask words for my 4 features (dword = 4 bool bytes).
    unsigned int m[FQ];
    #pragma unroll
    for (int j = 0; j < FQ; j++) m[j] = msk[base + j * PLANE4];

    unsigned int anyu = m[0] | m[1] | m[2] | m[3];
    anyu |= __shfl_xor(anyu, 16, 64);        // combine quarters...
    anyu |= __shfl_xor(anyu, 32, 64);        // ...-> any over all 16 features
    const float af0 = (anyu & 0x000000FFu) ? 1.f : 0.f;
    const float af1 = (anyu & 0x0000FF00u) ? 1.f : 0.f;
    const float af2 = (anyu & 0x00FF0000u) ? 1.f : 0.f;
    const float af3 = (anyu & 0xFF000000u) ? 1.f : 0.f;
    const float call = (q == 0) ? (af0 + af1) + (af2 + af3) : 0.f;  // count once

    float s[FQ], c[FQ], dtot[FQ], sall[FQ];
    #pragma unroll
    for (int j = 0; j < FQ; j++) {
        const float4 a = inp[base + j * PLANE4];
        const float4 t = tgt[base + j * PLANE4];
        const float d0 = fabsf(a.x - t.x);
        const float d1 = fabsf(a.y - t.y);
        const float d2 = fabsf(a.z - t.z);
        const float d3 = fabsf(a.w - t.w);
        const unsigned int mm = m[j];
        const float m0 = (float)( mm        & 0xFFu);
        const float m1 = (float)((mm >> 8)  & 0xFFu);
        const float m2 = (float)((mm >> 16) & 0xFFu);
        const float m3 = (float)( mm >> 24);
        dtot[j] = (d0 + d1) + (d2 + d3);
        s[j]    = m0 * d0 + m1 * d1 + m2 * d2 + m3 * d3;
        c[j]    = (m0 + m1) + (m2 + m3);
        sall[j] = af0 * d0 + af1 * d1 + af2 * d2 + af3 * d3;
    }

    // Width-16 reduction (quarters hold disjoint features), LDS across waves.
    __shared__ float red[NTHREADS / 64][NVALS];
    const int fbase = q * FQ;
    #pragma unroll
    for (int j = 0; j < FQ; j++) {
        float xs = s[j], xc = c[j], xd = dtot[j], xa = sall[j];
        #pragma unroll
        for (int o = 8; o > 0; o >>= 1) {
            xs += __shfl_down(xs, o, 16);
            xc += __shfl_down(xc, o, 16);
            xd += __shfl_down(xd, o, 16);
            xa += __shfl_down(xa, o, 16);
        }
        if (l16 == 0) {
            red[wave][ 0 + fbase + j] = xs;
            red[wave][16 + fbase + j] = xc;
            red[wave][32 + fbase + j] = xd;
            red[wave][48 + fbase + j] = xa;
        }
    }
    float xcall = call;
    #pragma unroll
    for (int o = 8; o > 0; o >>= 1) xcall += __shfl_down(xcall, o, 16);
    if (lane == 0) red[wave][64] = xcall;
    __syncthreads();
    if (tid < NVALS) {
        float t = 0.f;
        #pragma unroll
        for (int w2 = 0; w2 < NTHREADS / 64; w2++) t += red[w2][tid];
        partials[tid * NBLOCKS + blockIdx.x] = t;   // layout [65][NBLOCKS]
    }
}

// 8 waves; each wave sums one value's 1024 partials with coalesced loads.
__global__ __launch_bounds__(512) void heatloss_finalize(
        const float* __restrict__ partials, float* __restrict__ out) {
    __shared__ float vals[NVALS];
    const int wave = threadIdx.x >> 6;   // 0..7
    const int lane = threadIdx.x & 63;
    for (int v = wave; v < NVALS; v += 8) {
        const float* p = partials + v * NBLOCKS;
        float x = 0.f;
        #pragma unroll
        for (int i = 0; i < NBLOCKS / 64; i++) x += p[i * 64 + lane];
        #pragma unroll
        for (int o = 32; o > 0; o >>= 1) x += __shfl_down(x, o, 64);
        if (lane == 0) vals[v] = x;
    }
    __syncthreads();
    if (threadIdx.x == 0) {
        const float Nf = (float)SPATIAL;  // per-feature element count (B*H*W)
        const float call = vals[64];
        float lf = 0.f, lbg = 0.f, lall = 0.f;
        #pragma unroll
        for (int f = 0; f < F; f++) {
            const float sf = vals[f], cf = vals[16 + f];
            const float dt = vals[32 + f], sa = vals[48 + f];
            lf += (cf > 0.f) ? sf / cf : 0.f;
            const float sbg = dt - sf, cbg = Nf - cf;
            lbg += (cbg > 0.f) ? sbg / cbg : 0.f;
            lall += (call > 0.f) ? sa / call : 0.f;
        }
        out[0] = (lf / 16.f + lbg / 16.f + lall / 16.f) / 3.f;
    }
}

extern "C" void kernel_launch(void* const* d_in, const int* in_sizes, int n_in,
                              void* d_out, int out_size, void* d_ws, size_t ws_size,
                              hipStream_t stream) {
    const float4*       inp = (const float4*)d_in[0];
    const float4*       tgt = (const float4*)d_in[1];
    const unsigned int* msk = (const unsigned int*)d_in[2];   // jnp.bool_ -> 1 byte each
    float* out      = (float*)d_out;
    float* partials = (float*)d_ws;   // NVALS * NBLOCKS floats = 266 KB

    heatloss_main<<<NBLOCKS, NTHREADS, 0, stream>>>(inp, tgt, msk, partials);
    heatloss_finalize<<<1, 512, 0, stream>>>(partials, out);
}